// Round 10
// baseline (791.928 us; speedup 1.0000x reference)
//
#include <hip/hip_runtime.h>
#include <hip/hip_bf16.h>

#define BB 16
#define NI 2048
#define NA 2048
#define DD 256
#define KVB 32
#define NT (NA / KVB)    // 64
#define NTL (NT / 2)     // 32 per split
#define QTOT (BB * NI)   // 32768

typedef _Float16 half8 __attribute__((ext_vector_type(8)));
typedef __attribute__((ext_vector_type(4))) float f32x4;
typedef __attribute__((ext_vector_type(4))) unsigned int uint4v;

static __device__ __forceinline__ unsigned short f2h(float f) {
  union { _Float16 h; unsigned short u; } x; x.h = (_Float16)f; return x.u;
}
static __device__ __forceinline__ float h2f(unsigned short u) {
  union { _Float16 h; unsigned short u; } x; x.u = u; return (float)x.h;
}
static __device__ __forceinline__ unsigned int pk2(float a, float b) {
  return __builtin_bit_cast(unsigned int, __builtin_amdgcn_cvt_pkrtz(a, b));
}

// ---------------- prep: attendee -> kfrag + vfrag (fragment-ordered fp16) ----------------
// kfrag[b][kt][c(8)][jt(2)][lane(64)][e(8)]: lane=quad*16+l16 holds K[jb+jt*16+l16][c*32+quad*8+e]
// vfrag[b][kt][h(2)][dt(8)][lane(64)][e(8)]: lane holds V^T[h*128+dt*16+l16][jb + pi(quad,e)]
//   pi(quad,e) = (e>>2)*16 + 4*quad + (e&3)  — matches P's natural post-QK^T layout.
__global__ void prep_kernel(const float* __restrict__ a,
                            unsigned short* __restrict__ kfrag,
                            unsigned short* __restrict__ vfrag) {
  __shared__ float t[64][65];
  int bx = blockIdx.x;
  int b = bx >> 7;
  int r = bx & 127;
  int jt_t = r >> 2, dt_t = r & 3;
  int j0 = jt_t * 64, d0 = dt_t * 64;
  int tid = threadIdx.x;
  int rr = tid >> 4, c4 = tid & 15;
#pragma unroll
  for (int k = 0; k < 4; ++k) {
    int row = rr + k * 16;
    int j = j0 + row;
    int d = d0 + c4 * 4;
    float4 v = *(const float4*)(a + ((size_t)b * NA + j) * DD + d);
    ushort4 hh;
    hh.x = f2h(v.x); hh.y = f2h(v.y); hh.z = f2h(v.z); hh.w = f2h(v.w);
    int kt = j >> 5, jtf = (j >> 4) & 1, l16k = j & 15;
    int c = d >> 5, quad = (d >> 3) & 3, e = d & 7;
    *(ushort4*)(kfrag + ((size_t)b * NT + kt) * 8192 + c * 1024 + jtf * 512 +
                (quad * 16 + l16k) * 8 + e) = hh;
    t[row][c4 * 4 + 0] = v.x; t[row][c4 * 4 + 1] = v.y;
    t[row][c4 * 4 + 2] = v.z; t[row][c4 * 4 + 3] = v.w;
  }
  __syncthreads();
#pragma unroll
  for (int k = 0; k < 4; ++k) {
    int dl = rr + k * 16;
    int d = d0 + dl;
    int j = j0 + c4 * 4;              // 4 consecutive j
    ushort4 o;
    o.x = f2h(t[c4 * 4 + 0][dl]); o.y = f2h(t[c4 * 4 + 1][dl]);
    o.z = f2h(t[c4 * 4 + 2][dl]); o.w = f2h(t[c4 * 4 + 3][dl]);
    int kt = j >> 5;
    int quad = c4 & 3;                // pi-inverse: j=j0+4*c4+i -> quad=c4&3
    int jt = (c4 >> 2) & 1;           // e = jt*4 + i
    int hh_ = (d >> 7) & 1, dtl = (d >> 4) & 7, l16v = d & 15;
    *(ushort4*)(vfrag + ((size_t)b * NT + kt) * 8192 + hh_ * 4096 + dtl * 512 +
                (quad * 16 + l16v) * 8 + jt * 4) = o;
  }
}

// ---------------- tw: W -> W^T hi/lo fp16, row-XOR-swizzled [e][d] ----------------
__global__ void tw_kernel(const float* __restrict__ w,
                          unsigned short* __restrict__ wth,
                          unsigned short* __restrict__ wtl) {
  __shared__ float t[64][65];
  int bx = blockIdx.x;
  int dt = bx >> 2, et = bx & 3;
  int d0 = dt * 64, e0 = et * 64;
  int tid = threadIdx.x;
  int rr = tid >> 4, c4 = (tid & 15) * 4;
#pragma unroll
  for (int k = 0; k < 4; ++k) {
    int row = rr + k * 16;   // d index
    float4 v = *(const float4*)(w + (size_t)(d0 + row) * DD + e0 + c4);
    t[row][c4 + 0] = v.x; t[row][c4 + 1] = v.y; t[row][c4 + 2] = v.z; t[row][c4 + 3] = v.w;
  }
  __syncthreads();
#pragma unroll
  for (int k = 0; k < 4; ++k) {
    int e = rr + k * 16;
    int eg = e0 + e;
    ushort4 h, l;
    float v0 = t[c4 + 0][e]; h.x = f2h(v0); l.x = f2h(v0 - h2f(h.x));
    float v1 = t[c4 + 1][e]; h.y = f2h(v1); l.y = f2h(v1 - h2f(h.y));
    float v2 = t[c4 + 2][e]; h.z = f2h(v2); l.z = f2h(v2 - h2f(h.z));
    float v3 = t[c4 + 3][e]; h.w = f2h(v3); l.w = f2h(v3 - h2f(h.w));
    int dd = d0 + c4;
    int u = dd >> 3, sub = dd & 7;
    size_t off = (size_t)eg * DD + ((u ^ (eg & 7)) * 8) + sub;
    *(ushort4*)(wth + off) = h;
    *(ushort4*)(wtl + off) = l;
  }
}

// ---------------- Q = x @ W  (2-term fp16 MFMA), writes qf fp16 row-major ----------------
__global__ __launch_bounds__(256, 2) void qgemm_kernel(
    const float* __restrict__ x, const unsigned short* __restrict__ wth,
    const unsigned short* __restrict__ wtl, unsigned short* __restrict__ qf) {
  __shared__ unsigned short wb[2][64 * 256];   // 64 KB
  const int tid = threadIdx.x;
  const int lane = tid & 63;
  const int wv = tid >> 6;
  const int quad = lane >> 4;
  const int l16 = lane & 15;
  const int m0 = blockIdx.x * 64;

  half8 xf[8];
  {
    const float* xr = x + (size_t)(m0 + wv * 16 + l16) * DD;
#pragma unroll
    for (int c = 0; c < 8; ++c) {
      float4 a = *(const float4*)(xr + c * 32 + quad * 8);
      float4 b = *(const float4*)(xr + c * 32 + quad * 8 + 4);
      half8 v;
      v[0] = (_Float16)a.x; v[1] = (_Float16)a.y; v[2] = (_Float16)a.z; v[3] = (_Float16)a.w;
      v[4] = (_Float16)b.x; v[5] = (_Float16)b.y; v[6] = (_Float16)b.z; v[7] = (_Float16)b.w;
      xf[c] = v;
    }
  }

#pragma unroll 1
  for (int eg = 0; eg < 4; ++eg) {
    uint4 t0[8], t1[8];
    {
      const unsigned short* sh = wth + (size_t)(eg * 64) * DD;
      const unsigned short* sl = wtl + (size_t)(eg * 64) * DD;
#pragma unroll
      for (int i = 0; i < 8; ++i) {
        t0[i] = *(const uint4*)(sh + (i * 256 + tid) * 8);
        t1[i] = *(const uint4*)(sl + (i * 256 + tid) * 8);
      }
    }
    __syncthreads();
#pragma unroll
    for (int i = 0; i < 8; ++i) {
      *(uint4*)(wb[0] + (i * 256 + tid) * 8) = t0[i];
      *(uint4*)(wb[1] + (i * 256 + tid) * 8) = t1[i];
    }
    __syncthreads();
#pragma unroll
    for (int etl = 0; etl < 4; ++etl) {
      int rloc = etl * 16 + l16;
      f32x4 acc; acc[0] = acc[1] = acc[2] = acc[3] = 0.f;
#pragma unroll
      for (int c = 0; c < 8; ++c) {
        int off = rloc * DD + (((4 * c + quad) ^ (rloc & 7)) * 8);
        half8 wh = *(const half8*)(wb[0] + off);
        half8 wl = *(const half8*)(wb[1] + off);
        acc = __builtin_amdgcn_mfma_f32_16x16x32_f16(xf[c], wh, acc, 0, 0, 0);
        acc = __builtin_amdgcn_mfma_f32_16x16x32_f16(xf[c], wl, acc, 0, 0, 0);
      }
      int e = eg * 64 + etl * 16 + l16;
#pragma unroll
      for (int rg = 0; rg < 4; ++rg) {
        qf[(size_t)(m0 + wv * 16 + 4 * quad + rg) * DD + e] = f2h(acc[rg]);
      }
    }
  }
}

// ---------------- flash attention v9: v8 + split-K(2) + setprio ----------------
// Grid 1024 = 2 splits x 512 q-blocks -> 4 blocks/CU (16 waves/CU). Each block does
// 64 q x 32 kt, writes l-normalized fp16 partial O + (m,l) per row. combine merges.
__global__ __launch_bounds__(256, 4) void attn_kernel(
    const unsigned short* __restrict__ kfrag, const unsigned short* __restrict__ vfrag,
    const unsigned short* __restrict__ qf, unsigned short* __restrict__ op,
    float* __restrict__ mlf) {
  __shared__ unsigned short kls[2][KVB * DD];   // 2 x 16 KB

  const int tid = threadIdx.x;
  const int lane = tid & 63;
  const int wv = tid >> 6;       // 0..3
  const int p = wv >> 1;         // pair
  const int h = wv & 1;          // d-half
  const int quad = lane >> 4;
  const int l16 = lane & 15;

  int bx = blockIdx.x;
  int lbx = (bx & 7) * 128 + (bx >> 3);   // XCD-chunked (1024 = 8*128)
  const int sk = lbx >> 9;                // split 0/1
  const int rem = lbx & 511;
  const int b = rem >> 5;
  const int qbase = (rem & 31) * 64 + p * 32;

  const unsigned short* kfb = kfrag + ((size_t)b * NT + sk * NTL) * 8192;
  const unsigned short* vfb = vfrag + ((size_t)b * NT + sk * NTL) * 8192 + h * 4096;

  // Q fragments (both q-tiles of the pair)
  half8 qh[2][8];
#pragma unroll
  for (int qt = 0; qt < 2; ++qt) {
    const size_t qrow = ((size_t)b * NI + qbase + qt * 16 + l16) * DD;
#pragma unroll
    for (int c = 0; c < 8; ++c)
      qh[qt][c] = *(const half8*)(qf + qrow + c * 32 + quad * 8);
  }

  f32x4 acc[2][8];
#pragma unroll
  for (int qt = 0; qt < 2; ++qt)
#pragma unroll
    for (int dt = 0; dt < 8; ++dt) { acc[qt][dt][0] = 0.f; acc[qt][dt][1] = 0.f; acc[qt][dt][2] = 0.f; acc[qt][dt][3] = 0.f; }
  float m0r = -INFINITY, m1r = -INFINITY;
  float l0 = 0.f, l1 = 0.f;    // per-lane partial denominators

  // prologue: stage K tile 0 (linear coalesced copy)
  {
    const unsigned short* s = kfb;
#pragma unroll
    for (int i = 0; i < 4; ++i)
      *(uint4*)(&kls[0][0] + i * 2048 + tid * 8) = *(const uint4*)(s + i * 2048 + tid * 8);
  }
  __syncthreads();

#pragma unroll 1
  for (int kt = 0; kt < NTL; ++kt) {
    // ---- V loads (own d-half), fully coalesced, consumed in PV ----
    half8 vb[8];
#pragma unroll
    for (int dt = 0; dt < 8; ++dt)
      vb[dt] = *(const half8*)(vfb + (size_t)kt * 8192 + dt * 512 + lane * 8);

    // ---- K(kt+1) prefetch into regs (linear coalesced) ----
    uint4 kf[4];
    if (kt + 1 < NTL) {
      const unsigned short* s = kfb + (size_t)(kt + 1) * 8192;
#pragma unroll
      for (int i = 0; i < 4; ++i)
        kf[i] = *(const uint4*)(s + i * 2048 + tid * 8);
    }

    // ---- QK^T: S^T[32 j x 32 q] from contiguous LDS frags ----
    const unsigned short* kb = &kls[kt & 1][0];
    f32x4 st[2][2];
    st[0][0][0]=st[0][0][1]=st[0][0][2]=st[0][0][3]=0.f;
    st[0][1][0]=st[0][1][1]=st[0][1][2]=st[0][1][3]=0.f;
    st[1][0][0]=st[1][0][1]=st[1][0][2]=st[1][0][3]=0.f;
    st[1][1][0]=st[1][1][1]=st[1][1][2]=st[1][1][3]=0.f;
    __builtin_amdgcn_s_setprio(1);
#pragma unroll
    for (int c = 0; c < 8; ++c) {
      half8 k0 = *(const half8*)(kb + c * 1024 + lane * 8);         // jt=0
      half8 k1 = *(const half8*)(kb + c * 1024 + 512 + lane * 8);   // jt=1
      st[0][0] = __builtin_amdgcn_mfma_f32_16x16x32_f16(k0, qh[0][c], st[0][0], 0, 0, 0);
      st[1][0] = __builtin_amdgcn_mfma_f32_16x16x32_f16(k0, qh[1][c], st[1][0], 0, 0, 0);
      st[0][1] = __builtin_amdgcn_mfma_f32_16x16x32_f16(k1, qh[0][c], st[0][1], 0, 0, 0);
      st[1][1] = __builtin_amdgcn_mfma_f32_16x16x32_f16(k1, qh[1][c], st[1][1], 0, 0, 0);
    }
    __builtin_amdgcn_s_setprio(0);

    // ---- per-wave softmax (lane holds P[q=l16][j=jt*16+4*quad+rg]) ----
    float mt0 = fmaxf(fmaxf(fmaxf(st[0][0][0], st[0][0][1]), fmaxf(st[0][0][2], st[0][0][3])),
                      fmaxf(fmaxf(st[0][1][0], st[0][1][1]), fmaxf(st[0][1][2], st[0][1][3])));
    float mt1 = fmaxf(fmaxf(fmaxf(st[1][0][0], st[1][0][1]), fmaxf(st[1][0][2], st[1][0][3])),
                      fmaxf(fmaxf(st[1][1][0], st[1][1][1]), fmaxf(st[1][1][2], st[1][1][3])));
    mt0 = fmaxf(mt0, __shfl_xor(mt0, 16)); mt0 = fmaxf(mt0, __shfl_xor(mt0, 32));
    mt1 = fmaxf(mt1, __shfl_xor(mt1, 16)); mt1 = fmaxf(mt1, __shfl_xor(mt1, 32));
    bool upd = __any((mt0 > m0r + 8.f) || (mt1 > m1r + 8.f)) != 0;
    if (upd) {
      float mn0 = fmaxf(m0r, mt0), mn1 = fmaxf(m1r, mt1);
      float sc0 = __expf(m0r - mn0), sc1 = __expf(m1r - mn1);
      l0 *= sc0; l1 *= sc1;
#pragma unroll
      for (int rg = 0; rg < 4; ++rg) {
        float a0 = __shfl(sc0, 4 * quad + rg);
        float a1 = __shfl(sc1, 4 * quad + rg);
#pragma unroll
        for (int dt = 0; dt < 8; ++dt) { acc[0][dt][rg] *= a0; acc[1][dt][rg] *= a1; }
      }
      m0r = mn0; m1r = mn1;
    }

    // ---- exp + per-lane partial sums ----
    float e0[2][4], e1[2][4];
#pragma unroll
    for (int jt = 0; jt < 2; ++jt)
#pragma unroll
      for (int rg = 0; rg < 4; ++rg) {
        e0[jt][rg] = __expf(st[0][jt][rg] - m0r);
        e1[jt][rg] = __expf(st[1][jt][rg] - m1r);
      }
    l0 += ((e0[0][0] + e0[0][1]) + (e0[0][2] + e0[0][3])) +
          ((e0[1][0] + e0[1][1]) + (e0[1][2] + e0[1][3]));
    l1 += ((e1[0][0] + e1[0][1]) + (e1[0][2] + e1[0][3])) +
          ((e1[1][0] + e1[1][1]) + (e1[1][2] + e1[1][3]));

    // ---- P A-fragment: direct in-register pack (shared k-permutation with vfrag) ----
    half8 pa0, pa1;
    {
      uint4v pa0u = { pk2(e0[0][0], e0[0][1]), pk2(e0[0][2], e0[0][3]),
                      pk2(e0[1][0], e0[1][1]), pk2(e0[1][2], e0[1][3]) };
      uint4v pa1u = { pk2(e1[0][0], e1[0][1]), pk2(e1[0][2], e1[0][3]),
                      pk2(e1[1][0], e1[1][1]), pk2(e1[1][2], e1[1][3]) };
      pa0 = __builtin_bit_cast(half8, pa0u);
      pa1 = __builtin_bit_cast(half8, pa1u);
    }

    // ---- PV (own d-half) ----
    __builtin_amdgcn_s_setprio(1);
#pragma unroll
    for (int dt = 0; dt < 8; ++dt) {
      acc[0][dt] = __builtin_amdgcn_mfma_f32_16x16x32_f16(pa0, vb[dt], acc[0][dt], 0, 0, 0);
      acc[1][dt] = __builtin_amdgcn_mfma_f32_16x16x32_f16(pa1, vb[dt], acc[1][dt], 0, 0, 0);
    }
    __builtin_amdgcn_s_setprio(0);

    // ---- stage next K into other buffer (late: full-body latency cover) ----
    if (kt + 1 < NTL) {
      unsigned short* d = &kls[(kt + 1) & 1][0];
#pragma unroll
      for (int i = 0; i < 4; ++i)
        *(uint4*)(d + i * 2048 + tid * 8) = kf[i];
    }
    __syncthreads();
  }

  // ---- epilogue: reduce denominators, write normalized fp16 partial + (m,l) ----
  l0 += __shfl_xor(l0, 16); l0 += __shfl_xor(l0, 32);
  l1 += __shfl_xor(l1, 16); l1 += __shfl_xor(l1, 32);
  float inv0 = 1.0f / l0, inv1 = 1.0f / l1;
  unsigned short* opb = op + (size_t)sk * QTOT * DD + ((size_t)b * NI + qbase) * DD + h * 128;
#pragma unroll
  for (int rg = 0; rg < 4; ++rg) {
    float i0 = __shfl(inv0, 4 * quad + rg);
    float i1 = __shfl(inv1, 4 * quad + rg);
#pragma unroll
    for (int dt = 0; dt < 8; ++dt) {
      int d = dt * 16 + l16;
      opb[(size_t)(4 * quad + rg) * DD + d] = f2h(acc[0][dt][rg] * i0);
      opb[(size_t)(16 + 4 * quad + rg) * DD + d] = f2h(acc[1][dt][rg] * i1);
    }
  }
  if (h == 0 && quad == 0) {
    float2* mlp = (float2*)mlf;
    int bq = b * NI + qbase;
    mlp[(size_t)sk * QTOT + bq + l16] = make_float2(m0r, l0);
    mlp[(size_t)sk * QTOT + bq + 16 + l16] = make_float2(m1r, l1);
  }
}

// ---------------- combine: merge the two split-K partials ----------------
__global__ __launch_bounds__(256) void combine_kernel(
    const unsigned short* __restrict__ op, const float* __restrict__ mlf,
    float* __restrict__ out) {
  size_t t = (size_t)blockIdx.x * 256 + threadIdx.x;   // handles 8 elements
  size_t base = t * 8;
  size_t q = base >> 8;
  const float2* mlp = (const float2*)mlf;
  float2 ml0 = mlp[q];
  float2 ml1 = mlp[(size_t)QTOT + q];
  float M = fmaxf(ml0.x, ml1.x);
  float w0 = ml0.y * __expf(ml0.x - M);
  float w1 = ml1.y * __expf(ml1.x - M);
  float inv = 1.0f / (w0 + w1);
  float a0 = w0 * inv, a1 = w1 * inv;
  half8 p0 = *(const half8*)(op + base);
  half8 p1 = *(const half8*)(op + (size_t)QTOT * DD + base);
  float4 r0, r1;
  r0.x = a0 * (float)p0[0] + a1 * (float)p1[0];
  r0.y = a0 * (float)p0[1] + a1 * (float)p1[1];
  r0.z = a0 * (float)p0[2] + a1 * (float)p1[2];
  r0.w = a0 * (float)p0[3] + a1 * (float)p1[3];
  r1.x = a0 * (float)p0[4] + a1 * (float)p1[4];
  r1.y = a0 * (float)p0[5] + a1 * (float)p1[5];
  r1.z = a0 * (float)p0[6] + a1 * (float)p1[6];
  r1.w = a0 * (float)p0[7] + a1 * (float)p1[7];
  *(float4*)(out + base) = r0;
  *(float4*)(out + base + 4) = r1;
}

extern "C" void kernel_launch(void* const* d_in, const int* in_sizes, int n_in,
                              void* d_out, int out_size, void* d_ws, size_t ws_size,
                              hipStream_t stream) {
  const float* x = (const float*)d_in[0];        // [16,2048,256]
  const float* att = (const float*)d_in[1];      // [16,2048,256]
  const float* W = (const float*)d_in[2];        // [256,256]
  float* out = (float*)d_out;

  const size_t NE = (size_t)BB * NA * DD;        // 8388608
  unsigned short* w0    = (unsigned short*)d_ws;
  unsigned short* kfrag = w0;
  unsigned short* vfrag = w0 + NE;
  unsigned short* qfp   = w0 + 2 * NE;
  unsigned short* wth   = w0 + 3 * NE;
  unsigned short* wtl   = w0 + 3 * NE + (size_t)DD * DD;
  unsigned short* op    = w0 + 3 * NE + 2 * (size_t)DD * DD;       // 2*NE shorts
  float* mlf            = (float*)(w0 + 5 * NE + 2 * (size_t)DD * DD);  // 2*QTOT float2
  // total ws use ≈ 85 MB

  prep_kernel<<<2048, 256, 0, stream>>>(att, kfrag, vfrag);
  tw_kernel<<<16, 256, 0, stream>>>(W, wth, wtl);
  qgemm_kernel<<<512, 256, 0, stream>>>(x, wth, wtl, qfp);
  attn_kernel<<<1024, 256, 0, stream>>>(kfrag, vfrag, qfp, op, mlf);
  combine_kernel<<<4096, 256, 0, stream>>>(op, mlf, out);
}

// Round 11
// 201.459 us; speedup vs baseline: 3.9310x; 3.9310x over previous
//
#include <hip/hip_runtime.h>
#include <hip/hip_bf16.h>

#define BB 16
#define NI 2048
#define NA 2048
#define DD 256
#define KVB 32
#define NT (NA / KVB)    // 64

typedef _Float16 half8 __attribute__((ext_vector_type(8)));
typedef __attribute__((ext_vector_type(4))) float f32x4;
typedef __attribute__((ext_vector_type(4))) unsigned int uint4v;

typedef const unsigned int CGU __attribute__((address_space(1)));
typedef unsigned int LU __attribute__((address_space(3)));

static __device__ __forceinline__ unsigned short f2h(float f) {
  union { _Float16 h; unsigned short u; } x; x.h = (_Float16)f; return x.u;
}
static __device__ __forceinline__ float h2f(unsigned short u) {
  union { _Float16 h; unsigned short u; } x; x.u = u; return (float)x.h;
}
static __device__ __forceinline__ unsigned int pk2(float a, float b) {
  return __builtin_bit_cast(unsigned int, __builtin_amdgcn_cvt_pkrtz(a, b));
}
// async global->LDS, 16B/lane; dst is wave-uniform base (HW adds lane*16)
static __device__ __forceinline__ void gload16(const unsigned short* g, unsigned short* l) {
  __builtin_amdgcn_global_load_lds((CGU*)g, (LU*)l, 16, 0, 0);
}

// ---------------- prep: attendee -> kfrag + vfrag (fragment-ordered fp16) ----------------
// kfrag[b][kt][c(8)][jt(2)][lane(64)][e(8)]: lane=quad*16+l16 holds K[jb+jt*16+l16][c*32+quad*8+e]
// vfrag[b][kt][h(2)][dt(8)][lane(64)][e(8)]: lane holds V^T[h*128+dt*16+l16][jb + pi(quad,e)]
//   pi(quad,e) = (e>>2)*16 + 4*quad + (e&3)  — matches P's natural post-QK^T layout.
__global__ void prep_kernel(const float* __restrict__ a,
                            unsigned short* __restrict__ kfrag,
                            unsigned short* __restrict__ vfrag) {
  __shared__ float t[64][65];
  int bx = blockIdx.x;
  int b = bx >> 7;
  int r = bx & 127;
  int jt_t = r >> 2, dt_t = r & 3;
  int j0 = jt_t * 64, d0 = dt_t * 64;
  int tid = threadIdx.x;
  int rr = tid >> 4, c4 = tid & 15;
#pragma unroll
  for (int k = 0; k < 4; ++k) {
    int row = rr + k * 16;
    int j = j0 + row;
    int d = d0 + c4 * 4;
    float4 v = *(const float4*)(a + ((size_t)b * NA + j) * DD + d);
    ushort4 hh;
    hh.x = f2h(v.x); hh.y = f2h(v.y); hh.z = f2h(v.z); hh.w = f2h(v.w);
    int kt = j >> 5, jtf = (j >> 4) & 1, l16k = j & 15;
    int c = d >> 5, quad = (d >> 3) & 3, e = d & 7;
    *(ushort4*)(kfrag + ((size_t)b * NT + kt) * 8192 + c * 1024 + jtf * 512 +
                (quad * 16 + l16k) * 8 + e) = hh;
    t[row][c4 * 4 + 0] = v.x; t[row][c4 * 4 + 1] = v.y;
    t[row][c4 * 4 + 2] = v.z; t[row][c4 * 4 + 3] = v.w;
  }
  __syncthreads();
#pragma unroll
  for (int k = 0; k < 4; ++k) {
    int dl = rr + k * 16;
    int d = d0 + dl;
    int j = j0 + c4 * 4;              // 4 consecutive j
    ushort4 o;
    o.x = f2h(t[c4 * 4 + 0][dl]); o.y = f2h(t[c4 * 4 + 1][dl]);
    o.z = f2h(t[c4 * 4 + 2][dl]); o.w = f2h(t[c4 * 4 + 3][dl]);
    int kt = j >> 5;
    int quad = c4 & 3;                // pi-inverse: j=j0+4*c4+i -> quad=c4&3
    int jt = (c4 >> 2) & 1;           // e = jt*4 + i
    int hh_ = (d >> 7) & 1, dtl = (d >> 4) & 7, l16v = d & 15;
    *(ushort4*)(vfrag + ((size_t)b * NT + kt) * 8192 + hh_ * 4096 + dtl * 512 +
                (quad * 16 + l16v) * 8 + jt * 4) = o;
  }
}

// ---------------- tw: W -> W^T hi/lo fp16, row-XOR-swizzled [e][d] ----------------
__global__ void tw_kernel(const float* __restrict__ w,
                          unsigned short* __restrict__ wth,
                          unsigned short* __restrict__ wtl) {
  __shared__ float t[64][65];
  int bx = blockIdx.x;
  int dt = bx >> 2, et = bx & 3;
  int d0 = dt * 64, e0 = et * 64;
  int tid = threadIdx.x;
  int rr = tid >> 4, c4 = (tid & 15) * 4;
#pragma unroll
  for (int k = 0; k < 4; ++k) {
    int row = rr + k * 16;   // d index
    float4 v = *(const float4*)(w + (size_t)(d0 + row) * DD + e0 + c4);
    t[row][c4 + 0] = v.x; t[row][c4 + 1] = v.y; t[row][c4 + 2] = v.z; t[row][c4 + 3] = v.w;
  }
  __syncthreads();
#pragma unroll
  for (int k = 0; k < 4; ++k) {
    int e = rr + k * 16;
    int eg = e0 + e;
    ushort4 h, l;
    float v0 = t[c4 + 0][e]; h.x = f2h(v0); l.x = f2h(v0 - h2f(h.x));
    float v1 = t[c4 + 1][e]; h.y = f2h(v1); l.y = f2h(v1 - h2f(h.y));
    float v2 = t[c4 + 2][e]; h.z = f2h(v2); l.z = f2h(v2 - h2f(h.z));
    float v3 = t[c4 + 3][e]; h.w = f2h(v3); l.w = f2h(v3 - h2f(h.w));
    int dd = d0 + c4;
    int u = dd >> 3, sub = dd & 7;
    size_t off = (size_t)eg * DD + ((u ^ (eg & 7)) * 8) + sub;
    *(ushort4*)(wth + off) = h;
    *(ushort4*)(wtl + off) = l;
  }
}

// ---------------- Q = x @ W  (2-term fp16 MFMA), writes qf fp16 row-major ----------------
__global__ __launch_bounds__(256, 2) void qgemm_kernel(
    const float* __restrict__ x, const unsigned short* __restrict__ wth,
    const unsigned short* __restrict__ wtl, unsigned short* __restrict__ qf) {
  __shared__ unsigned short wb[2][64 * 256];   // 64 KB
  const int tid = threadIdx.x;
  const int lane = tid & 63;
  const int wv = tid >> 6;
  const int quad = lane >> 4;
  const int l16 = lane & 15;
  const int m0 = blockIdx.x * 64;

  half8 xf[8];
  {
    const float* xr = x + (size_t)(m0 + wv * 16 + l16) * DD;
#pragma unroll
    for (int c = 0; c < 8; ++c) {
      float4 a = *(const float4*)(xr + c * 32 + quad * 8);
      float4 b = *(const float4*)(xr + c * 32 + quad * 8 + 4);
      half8 v;
      v[0] = (_Float16)a.x; v[1] = (_Float16)a.y; v[2] = (_Float16)a.z; v[3] = (_Float16)a.w;
      v[4] = (_Float16)b.x; v[5] = (_Float16)b.y; v[6] = (_Float16)b.z; v[7] = (_Float16)b.w;
      xf[c] = v;
    }
  }

#pragma unroll 1
  for (int eg = 0; eg < 4; ++eg) {
    uint4 t0[8], t1[8];
    {
      const unsigned short* sh = wth + (size_t)(eg * 64) * DD;
      const unsigned short* sl = wtl + (size_t)(eg * 64) * DD;
#pragma unroll
      for (int i = 0; i < 8; ++i) {
        t0[i] = *(const uint4*)(sh + (i * 256 + tid) * 8);
        t1[i] = *(const uint4*)(sl + (i * 256 + tid) * 8);
      }
    }
    __syncthreads();
#pragma unroll
    for (int i = 0; i < 8; ++i) {
      *(uint4*)(wb[0] + (i * 256 + tid) * 8) = t0[i];
      *(uint4*)(wb[1] + (i * 256 + tid) * 8) = t1[i];
    }
    __syncthreads();
#pragma unroll
    for (int etl = 0; etl < 4; ++etl) {
      int rloc = etl * 16 + l16;
      f32x4 acc; acc[0] = acc[1] = acc[2] = acc[3] = 0.f;
#pragma unroll
      for (int c = 0; c < 8; ++c) {
        int off = rloc * DD + (((4 * c + quad) ^ (rloc & 7)) * 8);
        half8 wh = *(const half8*)(wb[0] + off);
        half8 wl = *(const half8*)(wb[1] + off);
        acc = __builtin_amdgcn_mfma_f32_16x16x32_f16(xf[c], wh, acc, 0, 0, 0);
        acc = __builtin_amdgcn_mfma_f32_16x16x32_f16(xf[c], wl, acc, 0, 0, 0);
      }
      int e = eg * 64 + etl * 16 + l16;
#pragma unroll
      for (int rg = 0; rg < 4; ++rg) {
        qf[(size_t)(m0 + wv * 16 + 4 * quad + rg) * DD + e] = f2h(acc[rg]);
      }
    }
  }
}

// ---------------- flash attention v11: 16-q waves, global_load_lds K staging, 4 blocks/CU ----------------
// 4 waves = 2 pairs x 2 d-halves; pair owns 16 q (both waves duplicate QK^T, split d in PV).
// Block = 32 q, grid 1024. K double-buffered in LDS via async global_load_lds (zero staging
// VGPRs, one barrier/kt drains DMA issued a full body earlier). V coalesced to regs.
// P in-register pack (shared k-permutation with vfrag). Target: VGPR+AGPR <= 128 -> 16 waves/CU.
__global__ __launch_bounds__(256, 4) void attn_kernel(
    const unsigned short* __restrict__ kfrag, const unsigned short* __restrict__ vfrag,
    const unsigned short* __restrict__ qf, float* __restrict__ out) {
  __shared__ unsigned short kls[2][KVB * DD];   // 2 x 16 KB

  const int tid = threadIdx.x;
  const int lane = tid & 63;
  const int wv = tid >> 6;       // 0..3
  const int p = wv >> 1;         // pair
  const int h = wv & 1;          // d-half
  const int quad = lane >> 4;
  const int l16 = lane & 15;

  int bx = blockIdx.x;
  int lbx = (bx & 7) * 128 + (bx >> 3);   // XCD-chunked (1024 = 8*128)
  const int b = lbx >> 6;
  const int qbase = (lbx & 63) * 32 + p * 16;

  const unsigned short* kfb = kfrag + (size_t)b * NT * 8192;
  const unsigned short* vfb = vfrag + (size_t)b * NT * 8192 + h * 4096;

  // Q fragments (16 q)
  half8 qh[8];
  {
    const size_t qrow = ((size_t)b * NI + qbase + l16) * DD;
#pragma unroll
    for (int c = 0; c < 8; ++c)
      qh[c] = *(const half8*)(qf + qrow + c * 32 + quad * 8);
  }

  f32x4 acc[8];
#pragma unroll
  for (int dt = 0; dt < 8; ++dt) { acc[dt][0] = 0.f; acc[dt][1] = 0.f; acc[dt][2] = 0.f; acc[dt][3] = 0.f; }
  float m0r = -INFINITY;
  float l0 = 0.f;               // per-lane partial denominator

  // prologue: DMA K tile 0 into kls[0] (4 x 1KB chunks per wave)
#pragma unroll
  for (int i = 0; i < 4; ++i) {
    int off = (i * 4 + wv) * 512;           // shorts
    gload16(kfb + off + lane * 8, &kls[0][off]);
  }
  __syncthreads();

#pragma unroll 1
  for (int kt = 0; kt < NT; ++kt) {
    // ---- V loads (own d-half), fully coalesced, consumed in PV ----
    half8 vb[8];
#pragma unroll
    for (int dt = 0; dt < 8; ++dt)
      vb[dt] = *(const half8*)(vfb + (size_t)kt * 8192 + dt * 512 + lane * 8);

    // ---- async DMA K(kt+1) into other buffer (drained by end-of-body barrier) ----
    if (kt + 1 < NT) {
      const unsigned short* s = kfb + (size_t)(kt + 1) * 8192;
      unsigned short* d = &kls[(kt + 1) & 1][0];
#pragma unroll
      for (int i = 0; i < 4; ++i) {
        int off = (i * 4 + wv) * 512;
        gload16(s + off + lane * 8, d + off);
      }
    }

    // ---- QK^T: S^T[32 j x 16 q] from contiguous LDS frags ----
    const unsigned short* kb = &kls[kt & 1][0];
    f32x4 st0, st1;
    st0[0] = st0[1] = st0[2] = st0[3] = 0.f;
    st1[0] = st1[1] = st1[2] = st1[3] = 0.f;
    __builtin_amdgcn_s_setprio(1);
#pragma unroll
    for (int c = 0; c < 8; ++c) {
      half8 k0 = *(const half8*)(kb + c * 1024 + lane * 8);         // jt=0
      half8 k1 = *(const half8*)(kb + c * 1024 + 512 + lane * 8);   // jt=1
      st0 = __builtin_amdgcn_mfma_f32_16x16x32_f16(k0, qh[c], st0, 0, 0, 0);
      st1 = __builtin_amdgcn_mfma_f32_16x16x32_f16(k1, qh[c], st1, 0, 0, 0);
    }
    __builtin_amdgcn_s_setprio(0);

    // ---- per-wave softmax (lane holds P[q=l16][j=jt*16+4*quad+rg]) ----
    float mt0 = fmaxf(fmaxf(fmaxf(st0[0], st0[1]), fmaxf(st0[2], st0[3])),
                      fmaxf(fmaxf(st1[0], st1[1]), fmaxf(st1[2], st1[3])));
    mt0 = fmaxf(mt0, __shfl_xor(mt0, 16)); mt0 = fmaxf(mt0, __shfl_xor(mt0, 32));
    bool upd = __any(mt0 > m0r + 8.f) != 0;
    if (upd) {
      float mn0 = fmaxf(m0r, mt0);
      float sc0 = __expf(m0r - mn0);
      l0 *= sc0;
#pragma unroll
      for (int rg = 0; rg < 4; ++rg) {
        float a0 = __shfl(sc0, 4 * quad + rg);
#pragma unroll
        for (int dt = 0; dt < 8; ++dt) acc[dt][rg] *= a0;
      }
      m0r = mn0;
    }

    // ---- exp + per-lane partial sum + in-register P pack ----
    float e00 = __expf(st0[0] - m0r), e01 = __expf(st0[1] - m0r);
    float e02 = __expf(st0[2] - m0r), e03 = __expf(st0[3] - m0r);
    float e10 = __expf(st1[0] - m0r), e11 = __expf(st1[1] - m0r);
    float e12 = __expf(st1[2] - m0r), e13 = __expf(st1[3] - m0r);
    l0 += ((e00 + e01) + (e02 + e03)) + ((e10 + e11) + (e12 + e13));
    half8 pa;
    {
      uint4v pau = { pk2(e00, e01), pk2(e02, e03), pk2(e10, e11), pk2(e12, e13) };
      pa = __builtin_bit_cast(half8, pau);
    }

    // ---- PV (own d-half) ----
    __builtin_amdgcn_s_setprio(1);
#pragma unroll
    for (int dt = 0; dt < 8; ++dt)
      acc[dt] = __builtin_amdgcn_mfma_f32_16x16x32_f16(pa, vb[dt], acc[dt], 0, 0, 0);
    __builtin_amdgcn_s_setprio(0);

    __syncthreads();   // drains DMA for kt+1; next iteration reads it
  }

  // ---- epilogue: reduce denominator, normalize, store ----
  l0 += __shfl_xor(l0, 16); l0 += __shfl_xor(l0, 32);
  float inv0 = 1.0f / l0;
  size_t ob = ((size_t)b * NI + qbase) * DD + h * 128;
#pragma unroll
  for (int rg = 0; rg < 4; ++rg) {
    float i0 = __shfl(inv0, 4 * quad + rg);
#pragma unroll
    for (int dt = 0; dt < 8; ++dt) {
      int d = dt * 16 + l16;
      out[ob + (size_t)(4 * quad + rg) * DD + d] = acc[dt][rg] * i0;
    }
  }
}

extern "C" void kernel_launch(void* const* d_in, const int* in_sizes, int n_in,
                              void* d_out, int out_size, void* d_ws, size_t ws_size,
                              hipStream_t stream) {
  const float* x = (const float*)d_in[0];        // [16,2048,256]
  const float* att = (const float*)d_in[1];      // [16,2048,256]
  const float* W = (const float*)d_in[2];        // [256,256]
  float* out = (float*)d_out;

  const size_t NE = (size_t)BB * NA * DD;        // 8388608
  unsigned short* w0    = (unsigned short*)d_ws;
  unsigned short* kfrag = w0;
  unsigned short* vfrag = w0 + NE;
  unsigned short* qfp   = w0 + 2 * NE;
  unsigned short* wth   = w0 + 3 * NE;
  unsigned short* wtl   = w0 + 3 * NE + (size_t)DD * DD;

  prep_kernel<<<2048, 256, 0, stream>>>(att, kfrag, vfrag);
  tw_kernel<<<16, 256, 0, stream>>>(W, wth, wtl);
  qgemm_kernel<<<512, 256, 0, stream>>>(x, wth, wtl, qfp);
  attn_kernel<<<1024, 256, 0, stream>>>(kfrag, vfrag, qfp, out);
}

// Round 12
// 201.456 us; speedup vs baseline: 3.9310x; 1.0000x over previous
//
#include <hip/hip_runtime.h>
#include <hip/hip_bf16.h>

#define BB 16
#define NI 2048
#define NA 2048
#define DD 256
#define KVB 32
#define NT (NA / KVB)    // 64

typedef _Float16 half8 __attribute__((ext_vector_type(8)));
typedef __attribute__((ext_vector_type(4))) float f32x4;
typedef __attribute__((ext_vector_type(4))) unsigned int uint4v;

typedef const unsigned int CGU __attribute__((address_space(1)));
typedef unsigned int LU __attribute__((address_space(3)));

static __device__ __forceinline__ unsigned short f2h(float f) {
  union { _Float16 h; unsigned short u; } x; x.h = (_Float16)f; return x.u;
}
static __device__ __forceinline__ float h2f(unsigned short u) {
  union { _Float16 h; unsigned short u; } x; x.u = u; return (float)x.h;
}
static __device__ __forceinline__ unsigned int pk2(float a, float b) {
  return __builtin_bit_cast(unsigned int, __builtin_amdgcn_cvt_pkrtz(a, b));
}
// async global->LDS, 16B/lane; dst is wave-uniform base (HW adds lane*16)
static __device__ __forceinline__ void gload16(const unsigned short* g, unsigned short* l) {
  __builtin_amdgcn_global_load_lds((CGU*)g, (LU*)l, 16, 0, 0);
}

// ---------------- prep (+fused tw): attendee -> kfrag + vfrag; W -> wth/wtl ----------------
// kfrag[b][kt][c(8)][jt(2)][lane(64)][e(8)]: lane=quad*16+l16 holds K[jb+jt*16+l16][c*32+quad*8+e]
// vfrag[b][kt][h(2)][dt(8)][lane(64)][e(8)]: lane holds V^T[h*128+dt*16+l16][jb + pi(quad,e)]
//   pi(quad,e) = (e>>2)*16 + 4*quad + (e&3)  — matches P's natural post-QK^T layout.
__global__ void prep_kernel(const float* __restrict__ a,
                            unsigned short* __restrict__ kfrag,
                            unsigned short* __restrict__ vfrag,
                            const float* __restrict__ w,
                            unsigned short* __restrict__ wth,
                            unsigned short* __restrict__ wtl) {
  __shared__ float t[64][65];
  int bx = blockIdx.x;
  int tid = threadIdx.x;
  int rr = tid >> 4, c4 = tid & 15;

  if (bx >= 2048) {
    // ---- tw: W -> W^T hi/lo fp16, row-XOR-swizzled [e][d] ----
    int r = bx - 2048;
    int dt = r >> 2, et = r & 3;
    int d0 = dt * 64, e0 = et * 64;
    int cc = c4 * 4;
#pragma unroll
    for (int k = 0; k < 4; ++k) {
      int row = rr + k * 16;   // d index
      float4 v = *(const float4*)(w + (size_t)(d0 + row) * DD + e0 + cc);
      t[row][cc + 0] = v.x; t[row][cc + 1] = v.y; t[row][cc + 2] = v.z; t[row][cc + 3] = v.w;
    }
    __syncthreads();
#pragma unroll
    for (int k = 0; k < 4; ++k) {
      int e = rr + k * 16;
      int eg = e0 + e;
      ushort4 h, l;
      float v0 = t[cc + 0][e]; h.x = f2h(v0); l.x = f2h(v0 - h2f(h.x));
      float v1 = t[cc + 1][e]; h.y = f2h(v1); l.y = f2h(v1 - h2f(h.y));
      float v2 = t[cc + 2][e]; h.z = f2h(v2); l.z = f2h(v2 - h2f(h.z));
      float v3 = t[cc + 3][e]; h.w = f2h(v3); l.w = f2h(v3 - h2f(h.w));
      int dd = d0 + cc;
      int u = dd >> 3, sub = dd & 7;
      size_t off = (size_t)eg * DD + ((u ^ (eg & 7)) * 8) + sub;
      *(ushort4*)(wth + off) = h;
      *(ushort4*)(wtl + off) = l;
    }
    return;
  }

  int b = bx >> 7;
  int r = bx & 127;
  int jt_t = r >> 2, dt_t = r & 3;
  int j0 = jt_t * 64, d0 = dt_t * 64;
#pragma unroll
  for (int k = 0; k < 4; ++k) {
    int row = rr + k * 16;
    int j = j0 + row;
    int d = d0 + c4 * 4;
    float4 v = *(const float4*)(a + ((size_t)b * NA + j) * DD + d);
    ushort4 hh;
    hh.x = f2h(v.x); hh.y = f2h(v.y); hh.z = f2h(v.z); hh.w = f2h(v.w);
    int kt = j >> 5, jtf = (j >> 4) & 1, l16k = j & 15;
    int c = d >> 5, quad = (d >> 3) & 3, e = d & 7;
    *(ushort4*)(kfrag + ((size_t)b * NT + kt) * 8192 + c * 1024 + jtf * 512 +
                (quad * 16 + l16k) * 8 + e) = hh;
    t[row][c4 * 4 + 0] = v.x; t[row][c4 * 4 + 1] = v.y;
    t[row][c4 * 4 + 2] = v.z; t[row][c4 * 4 + 3] = v.w;
  }
  __syncthreads();
#pragma unroll
  for (int k = 0; k < 4; ++k) {
    int dl = rr + k * 16;
    int d = d0 + dl;
    int j = j0 + c4 * 4;              // 4 consecutive j
    ushort4 o;
    o.x = f2h(t[c4 * 4 + 0][dl]); o.y = f2h(t[c4 * 4 + 1][dl]);
    o.z = f2h(t[c4 * 4 + 2][dl]); o.w = f2h(t[c4 * 4 + 3][dl]);
    int kt = j >> 5;
    int quad = c4 & 3;                // pi-inverse: j=j0+4*c4+i -> quad=c4&3
    int jt = (c4 >> 2) & 1;           // e = jt*4 + i
    int hh_ = (d >> 7) & 1, dtl = (d >> 4) & 7, l16v = d & 15;
    *(ushort4*)(vfrag + ((size_t)b * NT + kt) * 8192 + hh_ * 4096 + dtl * 512 +
                (quad * 16 + l16v) * 8 + jt * 4) = o;
  }
}

// ---------------- Q = (x @ W) * log2(e)  (2-term fp16 MFMA), writes qf fp16 row-major ----------------
// Pre-scaling by log2(e) moves attn softmax into exp2 domain (native v_exp).
__global__ __launch_bounds__(256, 2) void qgemm_kernel(
    const float* __restrict__ x, const unsigned short* __restrict__ wth,
    const unsigned short* __restrict__ wtl, unsigned short* __restrict__ qf) {
  __shared__ unsigned short wb[2][64 * 256];   // 64 KB
  const int tid = threadIdx.x;
  const int lane = tid & 63;
  const int wv = tid >> 6;
  const int quad = lane >> 4;
  const int l16 = lane & 15;
  const int m0 = blockIdx.x * 64;

  half8 xf[8];
  {
    const float* xr = x + (size_t)(m0 + wv * 16 + l16) * DD;
#pragma unroll
    for (int c = 0; c < 8; ++c) {
      float4 a = *(const float4*)(xr + c * 32 + quad * 8);
      float4 b = *(const float4*)(xr + c * 32 + quad * 8 + 4);
      half8 v;
      v[0] = (_Float16)a.x; v[1] = (_Float16)a.y; v[2] = (_Float16)a.z; v[3] = (_Float16)a.w;
      v[4] = (_Float16)b.x; v[5] = (_Float16)b.y; v[6] = (_Float16)b.z; v[7] = (_Float16)b.w;
      xf[c] = v;
    }
  }

#pragma unroll 1
  for (int eg = 0; eg < 4; ++eg) {
    uint4 t0[8], t1[8];
    {
      const unsigned short* sh = wth + (size_t)(eg * 64) * DD;
      const unsigned short* sl = wtl + (size_t)(eg * 64) * DD;
#pragma unroll
      for (int i = 0; i < 8; ++i) {
        t0[i] = *(const uint4*)(sh + (i * 256 + tid) * 8);
        t1[i] = *(const uint4*)(sl + (i * 256 + tid) * 8);
      }
    }
    __syncthreads();
#pragma unroll
    for (int i = 0; i < 8; ++i) {
      *(uint4*)(wb[0] + (i * 256 + tid) * 8) = t0[i];
      *(uint4*)(wb[1] + (i * 256 + tid) * 8) = t1[i];
    }
    __syncthreads();
#pragma unroll
    for (int etl = 0; etl < 4; ++etl) {
      int rloc = etl * 16 + l16;
      f32x4 acc; acc[0] = acc[1] = acc[2] = acc[3] = 0.f;
#pragma unroll
      for (int c = 0; c < 8; ++c) {
        int off = rloc * DD + (((4 * c + quad) ^ (rloc & 7)) * 8);
        half8 wh = *(const half8*)(wb[0] + off);
        half8 wl = *(const half8*)(wb[1] + off);
        acc = __builtin_amdgcn_mfma_f32_16x16x32_f16(xf[c], wh, acc, 0, 0, 0);
        acc = __builtin_amdgcn_mfma_f32_16x16x32_f16(xf[c], wl, acc, 0, 0, 0);
      }
      int e = eg * 64 + etl * 16 + l16;
#pragma unroll
      for (int rg = 0; rg < 4; ++rg) {
        qf[(size_t)(m0 + wv * 16 + 4 * quad + rg) * DD + e] = f2h(acc[rg] * 1.44269504f);
      }
    }
  }
}

// ---------------- flash attention v12: v11 + exp2 domain + fast-path softmax + split chains ----------------
__global__ __launch_bounds__(256, 4) void attn_kernel(
    const unsigned short* __restrict__ kfrag, const unsigned short* __restrict__ vfrag,
    const unsigned short* __restrict__ qf, float* __restrict__ out) {
  __shared__ unsigned short kls[2][KVB * DD];   // 2 x 16 KB

  const int tid = threadIdx.x;
  const int lane = tid & 63;
  const int wv = tid >> 6;       // 0..3
  const int p = wv >> 1;         // pair
  const int h = wv & 1;          // d-half
  const int quad = lane >> 4;
  const int l16 = lane & 15;

  int bx = blockIdx.x;
  int lbx = (bx & 7) * 128 + (bx >> 3);   // XCD-chunked (1024 = 8*128)
  const int b = lbx >> 6;
  const int qbase = (lbx & 63) * 32 + p * 16;

  const unsigned short* kfb = kfrag + (size_t)b * NT * 8192;
  const unsigned short* vfb = vfrag + (size_t)b * NT * 8192 + h * 4096;

  // Q fragments (16 q, log2e-prescaled)
  half8 qh[8];
  {
    const size_t qrow = ((size_t)b * NI + qbase + l16) * DD;
#pragma unroll
    for (int c = 0; c < 8; ++c)
      qh[c] = *(const half8*)(qf + qrow + c * 32 + quad * 8);
  }

  f32x4 acc[8];
#pragma unroll
  for (int dt = 0; dt < 8; ++dt) { acc[dt][0] = 0.f; acc[dt][1] = 0.f; acc[dt][2] = 0.f; acc[dt][3] = 0.f; }
  float m0r = -INFINITY;   // running row max (log2 units), uniform per q-row
  float l0 = 0.f;          // per-lane partial denominator

  // prologue: DMA K tile 0 into kls[0]
#pragma unroll
  for (int i = 0; i < 4; ++i) {
    int off = (i * 4 + wv) * 512;
    gload16(kfb + off + lane * 8, &kls[0][off]);
  }
  __syncthreads();

#pragma unroll 1
  for (int kt = 0; kt < NT; ++kt) {
    // ---- V loads (own d-half), fully coalesced ----
    half8 vb[8];
#pragma unroll
    for (int dt = 0; dt < 8; ++dt)
      vb[dt] = *(const half8*)(vfb + (size_t)kt * 8192 + dt * 512 + lane * 8);

    // ---- async DMA K(kt+1) (drained by end-of-body barrier) ----
    if (kt + 1 < NT) {
      const unsigned short* s = kfb + (size_t)(kt + 1) * 8192;
      unsigned short* d = &kls[(kt + 1) & 1][0];
#pragma unroll
      for (int i = 0; i < 4; ++i) {
        int off = (i * 4 + wv) * 512;
        gload16(s + off + lane * 8, d + off);
      }
    }

    // ---- QK^T: S^T[32 j x 16 q], split accumulation chains ----
    const unsigned short* kb = &kls[kt & 1][0];
    f32x4 sa0, sb0, sa1, sb1;
    sa0[0]=sa0[1]=sa0[2]=sa0[3]=0.f; sb0[0]=sb0[1]=sb0[2]=sb0[3]=0.f;
    sa1[0]=sa1[1]=sa1[2]=sa1[3]=0.f; sb1[0]=sb1[1]=sb1[2]=sb1[3]=0.f;
    __builtin_amdgcn_s_setprio(1);
#pragma unroll
    for (int c = 0; c < 4; ++c) {
      half8 k0 = *(const half8*)(kb + c * 1024 + lane * 8);
      half8 k1 = *(const half8*)(kb + c * 1024 + 512 + lane * 8);
      sa0 = __builtin_amdgcn_mfma_f32_16x16x32_f16(k0, qh[c], sa0, 0, 0, 0);
      sa1 = __builtin_amdgcn_mfma_f32_16x16x32_f16(k1, qh[c], sa1, 0, 0, 0);
    }
#pragma unroll
    for (int c = 4; c < 8; ++c) {
      half8 k0 = *(const half8*)(kb + c * 1024 + lane * 8);
      half8 k1 = *(const half8*)(kb + c * 1024 + 512 + lane * 8);
      sb0 = __builtin_amdgcn_mfma_f32_16x16x32_f16(k0, qh[c], sb0, 0, 0, 0);
      sb1 = __builtin_amdgcn_mfma_f32_16x16x32_f16(k1, qh[c], sb1, 0, 0, 0);
    }
    __builtin_amdgcn_s_setprio(0);
    f32x4 st0, st1;
    st0[0]=sa0[0]+sb0[0]; st0[1]=sa0[1]+sb0[1]; st0[2]=sa0[2]+sb0[2]; st0[3]=sa0[3]+sb0[3];
    st1[0]=sa1[0]+sb1[0]; st1[1]=sa1[1]+sb1[1]; st1[2]=sa1[2]+sb1[2]; st1[3]=sa1[3]+sb1[3];

    // ---- defer-max fast path: lane-local check; full reduce only on update ----
    float mt = fmaxf(fmaxf(fmaxf(st0[0], st0[1]), fmaxf(st0[2], st0[3])),
                     fmaxf(fmaxf(st1[0], st1[1]), fmaxf(st1[2], st1[3])));
    if (__any(mt > m0r + 11.5416f)) {       // 8 nats in log2 units
      float mr = fmaxf(mt, __shfl_xor(mt, 16));
      mr = fmaxf(mr, __shfl_xor(mr, 32));
      float mn = fmaxf(m0r, mr);
      float sc = exp2f(m0r - mn);
      l0 *= sc;
#pragma unroll
      for (int rg = 0; rg < 4; ++rg) {
        float a0 = __shfl(sc, 4 * quad + rg);
#pragma unroll
        for (int dt = 0; dt < 8; ++dt) acc[dt][rg] *= a0;
      }
      m0r = mn;
    }

    // ---- exp2 + per-lane partial sum + in-register P pack ----
    float e00 = exp2f(st0[0] - m0r), e01 = exp2f(st0[1] - m0r);
    float e02 = exp2f(st0[2] - m0r), e03 = exp2f(st0[3] - m0r);
    float e10 = exp2f(st1[0] - m0r), e11 = exp2f(st1[1] - m0r);
    float e12 = exp2f(st1[2] - m0r), e13 = exp2f(st1[3] - m0r);
    l0 += ((e00 + e01) + (e02 + e03)) + ((e10 + e11) + (e12 + e13));
    half8 pa;
    {
      uint4v pau = { pk2(e00, e01), pk2(e02, e03), pk2(e10, e11), pk2(e12, e13) };
      pa = __builtin_bit_cast(half8, pau);
    }

    // ---- PV (own d-half) ----
    __builtin_amdgcn_s_setprio(1);
#pragma unroll
    for (int dt = 0; dt < 8; ++dt)
      acc[dt] = __builtin_amdgcn_mfma_f32_16x16x32_f16(pa, vb[dt], acc[dt], 0, 0, 0);
    __builtin_amdgcn_s_setprio(0);

    __syncthreads();   // drains DMA for kt+1
  }

  // ---- epilogue ----
  l0 += __shfl_xor(l0, 16); l0 += __shfl_xor(l0, 32);
  float inv0 = 1.0f / l0;
  size_t ob = ((size_t)b * NI + qbase) * DD + h * 128;
#pragma unroll
  for (int rg = 0; rg < 4; ++rg) {
    float i0 = __shfl(inv0, 4 * quad + rg);
#pragma unroll
    for (int dt = 0; dt < 8; ++dt) {
      int d = dt * 16 + l16;
      out[ob + (size_t)(4 * quad + rg) * DD + d] = acc[dt][rg] * i0;
    }
  }
}

extern "C" void kernel_launch(void* const* d_in, const int* in_sizes, int n_in,
                              void* d_out, int out_size, void* d_ws, size_t ws_size,
                              hipStream_t stream) {
  const float* x = (const float*)d_in[0];        // [16,2048,256]
  const float* att = (const float*)d_in[1];      // [16,2048,256]
  const float* W = (const float*)d_in[2];        // [256,256]
  float* out = (float*)d_out;

  const size_t NE = (size_t)BB * NA * DD;        // 8388608
  unsigned short* w0    = (unsigned short*)d_ws;
  unsigned short* kfrag = w0;
  unsigned short* vfrag = w0 + NE;
  unsigned short* qfp   = w0 + 2 * NE;
  unsigned short* wth   = w0 + 3 * NE;
  unsigned short* wtl   = w0 + 3 * NE + (size_t)DD * DD;

  prep_kernel<<<2064, 256, 0, stream>>>(att, kfrag, vfrag, W, wth, wtl);
  qgemm_kernel<<<512, 256, 0, stream>>>(x, wth, wtl, qfp);
  attn_kernel<<<1024, 256, 0, stream>>>(kfrag, vfrag, qfp, out);
}

// Round 13
// 196.534 us; speedup vs baseline: 4.0295x; 1.0250x over previous
//
#include <hip/hip_runtime.h>
#include <hip/hip_bf16.h>

#define BB 16
#define NI 2048
#define NA 2048
#define DD 256
#define KVB 32
#define NT (NA / KVB)    // 64

typedef _Float16 half8 __attribute__((ext_vector_type(8)));
typedef _Float16 half2t __attribute__((ext_vector_type(2)));
typedef __attribute__((ext_vector_type(4))) float f32x4;
typedef __attribute__((ext_vector_type(4))) unsigned int uint4v;

typedef const unsigned int CGU __attribute__((address_space(1)));
typedef unsigned int LU __attribute__((address_space(3)));

static __device__ __forceinline__ unsigned short f2h(float f) {
  union { _Float16 h; unsigned short u; } x; x.h = (_Float16)f; return x.u;
}
static __device__ __forceinline__ float h2f(unsigned short u) {
  union { _Float16 h; unsigned short u; } x; x.u = u; return (float)x.h;
}
static __device__ __forceinline__ unsigned int pk2(float a, float b) {
  return __builtin_bit_cast(unsigned int, __builtin_amdgcn_cvt_pkrtz(a, b));
}
// async global->LDS, 16B/lane; dst is wave-uniform base (HW adds lane*16)
static __device__ __forceinline__ void gload16(const unsigned short* g, unsigned short* l) {
  __builtin_amdgcn_global_load_lds((CGU*)g, (LU*)l, 16, 0, 0);
}

// ---------------- prep (+fused tw): attendee -> kfrag + vfrag; W -> wth/wtl ----------------
// kfrag[b][kt][c(8)][jt(2)][lane(64)][e(8)]: lane=quad*16+l16 holds K[jb+jt*16+l16][c*32+quad*8+e]
// vfrag[b][kt][h(2)][dt(8)][lane(64)][e(8)]: lane holds V^T[h*128+dt*16+l16][jb + pi(quad,e)]
//   pi(quad,e) = (e>>2)*16 + 4*quad + (e&3)  — matches P's natural post-QK^T layout.
__global__ void prep_kernel(const float* __restrict__ a,
                            unsigned short* __restrict__ kfrag,
                            unsigned short* __restrict__ vfrag,
                            const float* __restrict__ w,
                            unsigned short* __restrict__ wth,
                            unsigned short* __restrict__ wtl) {
  __shared__ float t[64][65];
  int bx = blockIdx.x;
  int tid = threadIdx.x;
  int rr = tid >> 4, c4 = tid & 15;

  if (bx >= 2048) {
    // ---- tw: W -> W^T hi/lo fp16, row-XOR-swizzled [e][d] ----
    int r = bx - 2048;
    int dt = r >> 2, et = r & 3;
    int d0 = dt * 64, e0 = et * 64;
    int cc = c4 * 4;
#pragma unroll
    for (int k = 0; k < 4; ++k) {
      int row = rr + k * 16;   // d index
      float4 v = *(const float4*)(w + (size_t)(d0 + row) * DD + e0 + cc);
      t[row][cc + 0] = v.x; t[row][cc + 1] = v.y; t[row][cc + 2] = v.z; t[row][cc + 3] = v.w;
    }
    __syncthreads();
#pragma unroll
    for (int k = 0; k < 4; ++k) {
      int e = rr + k * 16;
      int eg = e0 + e;
      ushort4 h, l;
      float v0 = t[cc + 0][e]; h.x = f2h(v0); l.x = f2h(v0 - h2f(h.x));
      float v1 = t[cc + 1][e]; h.y = f2h(v1); l.y = f2h(v1 - h2f(h.y));
      float v2 = t[cc + 2][e]; h.z = f2h(v2); l.z = f2h(v2 - h2f(h.z));
      float v3 = t[cc + 3][e]; h.w = f2h(v3); l.w = f2h(v3 - h2f(h.w));
      int dd = d0 + cc;
      int u = dd >> 3, sub = dd & 7;
      size_t off = (size_t)eg * DD + ((u ^ (eg & 7)) * 8) + sub;
      *(ushort4*)(wth + off) = h;
      *(ushort4*)(wtl + off) = l;
    }
    return;
  }

  int b = bx >> 7;
  int r = bx & 127;
  int jt_t = r >> 2, dt_t = r & 3;
  int j0 = jt_t * 64, d0 = dt_t * 64;
#pragma unroll
  for (int k = 0; k < 4; ++k) {
    int row = rr + k * 16;
    int j = j0 + row;
    int d = d0 + c4 * 4;
    float4 v = *(const float4*)(a + ((size_t)b * NA + j) * DD + d);
    ushort4 hh;
    hh.x = f2h(v.x); hh.y = f2h(v.y); hh.z = f2h(v.z); hh.w = f2h(v.w);
    int kt = j >> 5, jtf = (j >> 4) & 1, l16k = j & 15;
    int c = d >> 5, quad = (d >> 3) & 3, e = d & 7;
    *(ushort4*)(kfrag + ((size_t)b * NT + kt) * 8192 + c * 1024 + jtf * 512 +
                (quad * 16 + l16k) * 8 + e) = hh;
    t[row][c4 * 4 + 0] = v.x; t[row][c4 * 4 + 1] = v.y;
    t[row][c4 * 4 + 2] = v.z; t[row][c4 * 4 + 3] = v.w;
  }
  __syncthreads();
#pragma unroll
  for (int k = 0; k < 4; ++k) {
    int dl = rr + k * 16;
    int d = d0 + dl;
    int j = j0 + c4 * 4;              // 4 consecutive j
    ushort4 o;
    o.x = f2h(t[c4 * 4 + 0][dl]); o.y = f2h(t[c4 * 4 + 1][dl]);
    o.z = f2h(t[c4 * 4 + 2][dl]); o.w = f2h(t[c4 * 4 + 3][dl]);
    int kt = j >> 5;
    int quad = c4 & 3;                // pi-inverse: j=j0+4*c4+i -> quad=c4&3
    int jt = (c4 >> 2) & 1;           // e = jt*4 + i
    int hh_ = (d >> 7) & 1, dtl = (d >> 4) & 7, l16v = d & 15;
    *(ushort4*)(vfrag + ((size_t)b * NT + kt) * 8192 + hh_ * 4096 + dtl * 512 +
                (quad * 16 + l16v) * 8 + jt * 4) = o;
  }
}

// ---------------- Q = (x @ W) * log2(e)  (2-term fp16 MFMA), writes qf fp16 row-major ----------------
__global__ __launch_bounds__(256, 2) void qgemm_kernel(
    const float* __restrict__ x, const unsigned short* __restrict__ wth,
    const unsigned short* __restrict__ wtl, unsigned short* __restrict__ qf) {
  __shared__ unsigned short wb[2][64 * 256];   // 64 KB
  const int tid = threadIdx.x;
  const int lane = tid & 63;
  const int wv = tid >> 6;
  const int quad = lane >> 4;
  const int l16 = lane & 15;
  const int m0 = blockIdx.x * 64;

  half8 xf[8];
  {
    const float* xr = x + (size_t)(m0 + wv * 16 + l16) * DD;
#pragma unroll
    for (int c = 0; c < 8; ++c) {
      float4 a = *(const float4*)(xr + c * 32 + quad * 8);
      float4 b = *(const float4*)(xr + c * 32 + quad * 8 + 4);
      half8 v;
      v[0] = (_Float16)a.x; v[1] = (_Float16)a.y; v[2] = (_Float16)a.z; v[3] = (_Float16)a.w;
      v[4] = (_Float16)b.x; v[5] = (_Float16)b.y; v[6] = (_Float16)b.z; v[7] = (_Float16)b.w;
      xf[c] = v;
    }
  }

#pragma unroll 1
  for (int eg = 0; eg < 4; ++eg) {
    uint4 t0[8], t1[8];
    {
      const unsigned short* sh = wth + (size_t)(eg * 64) * DD;
      const unsigned short* sl = wtl + (size_t)(eg * 64) * DD;
#pragma unroll
      for (int i = 0; i < 8; ++i) {
        t0[i] = *(const uint4*)(sh + (i * 256 + tid) * 8);
        t1[i] = *(const uint4*)(sl + (i * 256 + tid) * 8);
      }
    }
    __syncthreads();
#pragma unroll
    for (int i = 0; i < 8; ++i) {
      *(uint4*)(wb[0] + (i * 256 + tid) * 8) = t0[i];
      *(uint4*)(wb[1] + (i * 256 + tid) * 8) = t1[i];
    }
    __syncthreads();
#pragma unroll
    for (int etl = 0; etl < 4; ++etl) {
      int rloc = etl * 16 + l16;
      f32x4 acc; acc[0] = acc[1] = acc[2] = acc[3] = 0.f;
#pragma unroll
      for (int c = 0; c < 8; ++c) {
        int off = rloc * DD + (((4 * c + quad) ^ (rloc & 7)) * 8);
        half8 wh = *(const half8*)(wb[0] + off);
        half8 wl = *(const half8*)(wb[1] + off);
        acc = __builtin_amdgcn_mfma_f32_16x16x32_f16(xf[c], wh, acc, 0, 0, 0);
        acc = __builtin_amdgcn_mfma_f32_16x16x32_f16(xf[c], wl, acc, 0, 0, 0);
      }
      int e = eg * 64 + etl * 16 + l16;
#pragma unroll
      for (int rg = 0; rg < 4; ++rg) {
        qf[(size_t)(m0 + wv * 16 + 4 * quad + rg) * DD + e] = f2h(acc[rg] * 1.44269504f);
      }
    }
  }
}

// ---------------- flash attention v13: j-split QK^T + raw-score exchange ----------------
// 4 waves = 2 pairs x 2 j/d-halves; pair owns 16 q. Wave h computes S^T for its j-half
// only (8 MFMA, 8 K LDS reads), exchanges raw fp16 scores through double-buffered LDS
// at the existing per-kt barrier, then runs self-consistent softmax over all 32 j and
// PV for its d-half. One barrier/kt total.
__global__ __launch_bounds__(256, 4) void attn_kernel(
    const unsigned short* __restrict__ kfrag, const unsigned short* __restrict__ vfrag,
    const unsigned short* __restrict__ qf, float* __restrict__ out) {
  __shared__ unsigned short kls[2][KVB * DD];   // 32 KB
  __shared__ uint2 sx[2][2][2][64];             // 4 KB [buf][pair][h][lane]

  const int tid = threadIdx.x;
  const int lane = tid & 63;
  const int wv = tid >> 6;       // 0..3
  const int p = wv >> 1;         // pair
  const int h = wv & 1;          // j-half (QK^T) and d-half (PV)
  const int quad = lane >> 4;
  const int l16 = lane & 15;

  int bx = blockIdx.x;
  int lbx = (bx & 7) * 128 + (bx >> 3);   // XCD-chunked (1024 = 8*128)
  const int b = lbx >> 6;
  const int qbase = (lbx & 63) * 32 + p * 16;

  const unsigned short* kfb = kfrag + (size_t)b * NT * 8192;
  const unsigned short* vfb = vfrag + (size_t)b * NT * 8192 + h * 4096;

  // Q fragments (16 q, log2e-prescaled)
  half8 qh[8];
  {
    const size_t qrow = ((size_t)b * NI + qbase + l16) * DD;
#pragma unroll
    for (int c = 0; c < 8; ++c)
      qh[c] = *(const half8*)(qf + qrow + c * 32 + quad * 8);
  }

  f32x4 acc[8];
#pragma unroll
  for (int dt = 0; dt < 8; ++dt) { acc[dt][0] = 0.f; acc[dt][1] = 0.f; acc[dt][2] = 0.f; acc[dt][3] = 0.f; }
  float m0r = -INFINITY;   // running row max (log2 units)
  float l0 = 0.f;          // per-lane partial denominator

  // prologue: DMA K tile 0 into kls[0]
#pragma unroll
  for (int i = 0; i < 4; ++i) {
    int off = (i * 4 + wv) * 512;
    gload16(kfb + off + lane * 8, &kls[0][off]);
  }
  __syncthreads();

#pragma unroll 1
  for (int kt = 0; kt < NT; ++kt) {
    // ---- V loads (own d-half), fully coalesced ----
    half8 vb[8];
#pragma unroll
    for (int dt = 0; dt < 8; ++dt)
      vb[dt] = *(const half8*)(vfb + (size_t)kt * 8192 + dt * 512 + lane * 8);

    // ---- async DMA K(kt+1) (drained by this kt's barrier) ----
    if (kt + 1 < NT) {
      const unsigned short* s = kfb + (size_t)(kt + 1) * 8192;
      unsigned short* d = &kls[(kt + 1) & 1][0];
#pragma unroll
      for (int i = 0; i < 4; ++i) {
        int off = (i * 4 + wv) * 512;
        gload16(s + off + lane * 8, d + off);
      }
    }

    // ---- QK^T: own j-half only (16 j x 16 q), split chains ----
    const unsigned short* kb = &kls[kt & 1][0];
    f32x4 sa, sb;
    sa[0]=sa[1]=sa[2]=sa[3]=0.f; sb[0]=sb[1]=sb[2]=sb[3]=0.f;
    __builtin_amdgcn_s_setprio(1);
#pragma unroll
    for (int c = 0; c < 4; ++c) {
      half8 k0 = *(const half8*)(kb + c * 1024 + h * 512 + lane * 8);
      sa = __builtin_amdgcn_mfma_f32_16x16x32_f16(k0, qh[c], sa, 0, 0, 0);
    }
#pragma unroll
    for (int c = 4; c < 8; ++c) {
      half8 k0 = *(const half8*)(kb + c * 1024 + h * 512 + lane * 8);
      sb = __builtin_amdgcn_mfma_f32_16x16x32_f16(k0, qh[c], sb, 0, 0, 0);
    }
    __builtin_amdgcn_s_setprio(0);
    f32x4 s;
    s[0] = sa[0] + sb[0]; s[1] = sa[1] + sb[1];
    s[2] = sa[2] + sb[2]; s[3] = sa[3] + sb[3];

    // ---- write own raw scores (fp16) for partner ----
    sx[kt & 1][p][h][lane] = make_uint2(pk2(s[0], s[1]), pk2(s[2], s[3]));
    __syncthreads();   // S exchange visible + K(kt+1) DMA drained

    // ---- read partner's half, unpack ----
    uint2 ox = sx[kt & 1][p][h ^ 1][lane];
    half2t oa = __builtin_bit_cast(half2t, ox.x);
    half2t ob = __builtin_bit_cast(half2t, ox.y);
    float o0 = (float)oa[0], o1 = (float)oa[1];
    float o2 = (float)ob[0], o3 = (float)ob[1];

    // ---- defer-max fast path over all 32 j ----
    float mt = fmaxf(fmaxf(fmaxf(s[0], s[1]), fmaxf(s[2], s[3])),
                     fmaxf(fmaxf(o0, o1), fmaxf(o2, o3)));
    if (__any(mt > m0r + 11.5416f)) {       // 8 nats in log2 units
      float mr = fmaxf(mt, __shfl_xor(mt, 16));
      mr = fmaxf(mr, __shfl_xor(mr, 32));
      float mn = fmaxf(m0r, mr);
      float sc = exp2f(m0r - mn);
      l0 *= sc;
#pragma unroll
      for (int rg = 0; rg < 4; ++rg) {
        float a0 = __shfl(sc, 4 * quad + rg);
#pragma unroll
        for (int dt = 0; dt < 8; ++dt) acc[dt][rg] *= a0;
      }
      m0r = mn;
    }

    // ---- exp2 over all 32 j + per-lane partial sum + P pack ----
    float es0 = exp2f(s[0] - m0r), es1 = exp2f(s[1] - m0r);
    float es2 = exp2f(s[2] - m0r), es3 = exp2f(s[3] - m0r);
    float eo0 = exp2f(o0 - m0r), eo1 = exp2f(o1 - m0r);
    float eo2 = exp2f(o2 - m0r), eo3 = exp2f(o3 - m0r);
    l0 += ((es0 + es1) + (es2 + es3)) + ((eo0 + eo1) + (eo2 + eo3));
    // own dwords cover jt=h, partner's cover jt=h^1; pa dword order = {jt0, jt0, jt1, jt1}
    unsigned int d0 = pk2(es0, es1), d1 = pk2(es2, es3);
    unsigned int c0 = pk2(eo0, eo1), c1 = pk2(eo2, eo3);
    uint4v pau;
    if (h == 0) { pau[0] = d0; pau[1] = d1; pau[2] = c0; pau[3] = c1; }
    else        { pau[0] = c0; pau[1] = c1; pau[2] = d0; pau[3] = d1; }
    half8 pa = __builtin_bit_cast(half8, pau);

    // ---- PV (own d-half) ----
    __builtin_amdgcn_s_setprio(1);
#pragma unroll
    for (int dt = 0; dt < 8; ++dt)
      acc[dt] = __builtin_amdgcn_mfma_f32_16x16x32_f16(pa, vb[dt], acc[dt], 0, 0, 0);
    __builtin_amdgcn_s_setprio(0);
    // no end-of-body barrier: sx is double-buffered, kls[b] overwrite for kt+2
    // happens only after kt+1's barrier (postdates all kt reads)
  }

  // ---- epilogue ----
  l0 += __shfl_xor(l0, 16); l0 += __shfl_xor(l0, 32);
  float inv0 = 1.0f / l0;
  size_t ob = ((size_t)b * NI + qbase) * DD + h * 128;
#pragma unroll
  for (int rg = 0; rg < 4; ++rg) {
    float i0 = __shfl(inv0, 4 * quad + rg);
#pragma unroll
    for (int dt = 0; dt < 8; ++dt) {
      int d = dt * 16 + l16;
      out[ob + (size_t)(4 * quad + rg) * DD + d] = acc[dt][rg] * i0;
    }
  }
}

extern "C" void kernel_launch(void* const* d_in, const int* in_sizes, int n_in,
                              void* d_out, int out_size, void* d_ws, size_t ws_size,
                              hipStream_t stream) {
  const float* x = (const float*)d_in[0];        // [16,2048,256]
  const float* att = (const float*)d_in[1];      // [16,2048,256]
  const float* W = (const float*)d_in[2];        // [256,256]
  float* out = (float*)d_out;

  const size_t NE = (size_t)BB * NA * DD;        // 8388608
  unsigned short* w0    = (unsigned short*)d_ws;
  unsigned short* kfrag = w0;
  unsigned short* vfrag = w0 + NE;
  unsigned short* qfp   = w0 + 2 * NE;
  unsigned short* wth   = w0 + 3 * NE;
  unsigned short* wtl   = w0 + 3 * NE + (size_t)DD * DD;

  prep_kernel<<<2064, 256, 0, stream>>>(att, kfrag, vfrag, W, wth, wtl);
  qgemm_kernel<<<512, 256, 0, stream>>>(x, wth, wtl, qfp);
  attn_kernel<<<1024, 256, 0, stream>>>(kfrag, vfrag, qfp, out);
}